// Round 8
// baseline (197.643 us; speedup 1.0000x reference)
//
#include <hip/hip_runtime.h>
#include <math.h>

#define NPTS 4096
#define CDIM 512
#define NROWS 16384
#define NTILES 528   // 32*33/2 tri-tiles of 128 per batch
#define FLTMAX 3.402823466e+38f

typedef _Float16 half_t;
typedef _Float16 half8 __attribute__((ext_vector_type(8)));
typedef float f32x4 __attribute__((ext_vector_type(4)));

__device__ inline void gl_lds16(const void* g, void* l) {
    __builtin_amdgcn_global_load_lds(
        (const __attribute__((address_space(1))) uint32_t*)g,
        (__attribute__((address_space(3))) uint32_t*)l, 16, 0, 0);
}

__device__ __forceinline__ int tri_start(int i) { return 32 * i - (i * (i - 1)) / 2; }

// ============================================================================
// Path A: prep -> fcm_sym (128x128 tri tiles, 8 waves: 2x2 output grid x
// kc-split pairs for TLP) -> combine
// Global f16 image: row stride 1024 B; 8 Kblocks of 64 ch (128 B); 16B slot s
// of each Kblock stored at position s^(row&7) (pre-baked LDS swizzle).
// ============================================================================

__global__ __launch_bounds__(256) void prep_kernel(const float* __restrict__ x,
                                                   half_t* __restrict__ hi,
                                                   float* __restrict__ sq) {
    const int wv = threadIdx.x >> 6, l = threadIdx.x & 63;
    const int row = blockIdx.x * 4 + wv;
    const float* f = x + (size_t)row * CDIM;
    float4 v0 = *(const float4*)(f + l * 8);
    float4 v1 = *(const float4*)(f + l * 8 + 4);
    float xs[8] = {v0.x, v0.y, v0.z, v0.w, v1.x, v1.y, v1.z, v1.w};
    half8 h;
    float s = 0.0f;
    #pragma unroll
    for (int i = 0; i < 8; ++i) {
        float v = xs[i];
        s = fmaf(v, v, s);
        h[i] = (half_t)v;
    }
    #pragma unroll
    for (int o = 32; o > 0; o >>= 1) s += __shfl_xor(s, o);
    const int kb = l >> 3;
    const int pos = (l & 7) ^ (row & 7);
    *(half8*)(hi + (size_t)row * CDIM + kb * 64 + pos * 8) = h;
    if (l == 0) sq[row] = s;
}

// One block per triangular tile (I,J), J>=I, per batch. 128x128 tile, BK=64,
// double-buffered LDS via global_load_lds, XCD-chunked tile order (bijective).
// 8 waves = (wm,wn) 2x2 output grid x wk in {0,1} kc-halves: wave pairs share
// one 64x64 output, each covering 32 of the 64 channels per K-step (pure-TLP
// split; per-wave work halves, totals unchanged, 16 waves/CU).
// Epilogue: wk=1 dumps acc to smem scratch; wk=0 adds, then folds:
// row-side -> slot 2J+wn; col-side (skip if I==J) -> slot 2I+wm.
// part layout: [slot][row] float4 (m0,m1,m2,max), d^2 domain.
__global__ __launch_bounds__(512, 4) void fcm_sym(const half_t* __restrict__ hi,
                                                  const float* __restrict__ sq,
                                                  float4* __restrict__ part4) {
    __shared__ __align__(16) char smem[2][2][16384];
    const int tid = threadIdx.x, wv = tid >> 6, l = tid & 63;
    const int wk = wv & 1, wn = (wv >> 1) & 1, wm = wv >> 2;
    const int wg = blockIdx.x;
    const int tl = (wg & 7) * 264 + (wg >> 3);        // XCD-chunked, bijective
    const int batch = tl / NTILES;
    const int t = tl - batch * NTILES;
    int I = (int)((65.0f - sqrtf(4225.0f - 8.0f * (float)t)) * 0.5f);
    while (tri_start(I + 1) <= t) ++I;
    while (tri_start(I) > t) --I;
    const int J = I + (t - tri_start(I));
    const int r0 = (batch << 12) + I * 128;
    const int c0 = (batch << 12) + J * 128;
    const char* base = (const char*)hi;

    // fragment byte offsets within A/B LDS buffers: this wave reads only its
    // wk half of the 8 slots (slot index = (l>>4) + wk*4, XOR row&7 pre-baked)
    int aoff[4], boff[4];
    #pragma unroll
    for (int q = 0; q < 4; ++q) {
        int rowa = wm * 64 + q * 16 + (l & 15);
        aoff[q] = rowa * 128 + ((((l >> 4) + wk * 4) ^ (rowa & 7)) * 16);
        int rowb = wn * 64 + q * 16 + (l & 15);
        boff[q] = rowb * 128 + ((((l >> 4) + wk * 4) ^ (rowb & 7)) * 16);
    }

    // stage addressing: 512 threads cover 16 KB per matrix per K-step in 2 chunks
    int srow[2], sin[2];
    #pragma unroll
    for (int i = 0; i < 2; ++i) {
        int dl = i * 8192 + wv * 1024 + l * 16;
        srow[i] = dl >> 7;
        sin[i] = dl & 127;
    }

#define STAGE(buf, ksv) do {                                                   \
        _Pragma("unroll")                                                      \
        for (int i_ = 0; i_ < 2; ++i_) {                                       \
            const int db_ = i_ * 8192 + wv * 1024;                             \
            gl_lds16(base + (size_t)(r0 + srow[i_]) * 1024 + (ksv) * 128 + sin[i_], \
                     &smem[buf][0][db_]);                                      \
            gl_lds16(base + (size_t)(c0 + srow[i_]) * 1024 + (ksv) * 128 + sin[i_], \
                     &smem[buf][1][db_]);                                      \
        } } while (0)

    f32x4 acc[4][4];
    #pragma unroll
    for (int mi = 0; mi < 4; ++mi)
        #pragma unroll
        for (int ni = 0; ni < 4; ++ni)
            #pragma unroll
            for (int j = 0; j < 4; ++j) acc[mi][ni][j] = 0.0f;

    STAGE(0, 0);
    __syncthreads();
    #pragma unroll
    for (int ks = 0; ks < 8; ++ks) {
        const int cur = ks & 1;
        if (ks < 7) STAGE(cur ^ 1, ks + 1);
        half8 af[4], bf[4];
        #pragma unroll
        for (int q = 0; q < 4; ++q) {
            af[q] = *(const half8*)&smem[cur][0][aoff[q]];
            bf[q] = *(const half8*)&smem[cur][1][boff[q]];
        }
        #pragma unroll
        for (int mi = 0; mi < 4; ++mi)
            #pragma unroll
            for (int ni = 0; ni < 4; ++ni)
                acc[mi][ni] = __builtin_amdgcn_mfma_f32_16x16x32_f16(
                    af[mi], bf[ni], acc[mi][ni], 0, 0, 0);
        __syncthreads();
    }
#undef STAGE

    // ---- merge wk pairs through LDS scratch (aliases the staging buffers;
    // safe: last barrier above drained all reads and gl_lds writes) ----
    f32x4* scr = (f32x4*)&smem[0][0][0];              // 64 KB = 4 pairs x 16 KB
    const int region = (wm * 2 + wn) * 1024;          // in f32x4 units
    if (wk == 1) {
        #pragma unroll
        for (int mi = 0; mi < 4; ++mi)
            #pragma unroll
            for (int ni = 0; ni < 4; ++ni)
                scr[region + (mi * 4 + ni) * 64 + l] = acc[mi][ni];
    }
    __syncthreads();
    if (wk == 1) return;
    #pragma unroll
    for (int mi = 0; mi < 4; ++mi)
        #pragma unroll
        for (int ni = 0; ni < 4; ++ni) {
            f32x4 o = scr[region + (mi * 4 + ni) * 64 + l];
            #pragma unroll
            for (int j = 0; j < 4; ++j) acc[mi][ni][j] += o[j];
        }

    // epilogue sq values
    float sr[16];
    #pragma unroll
    for (int mi = 0; mi < 4; ++mi)
        #pragma unroll
        for (int j = 0; j < 4; ++j)
            sr[mi * 4 + j] = sq[r0 + wm * 64 + mi * 16 + (l >> 4) * 4 + j];
    float scn[4];
    #pragma unroll
    for (int ni = 0; ni < 4; ++ni)
        scn[ni] = sq[c0 + wn * 64 + ni * 16 + (l & 15)];

    // ---- row-side fold: rows of block I over this tile's 128 cols ----
    float st0[16], st1[16], st2[16], stx[16];
    #pragma unroll
    for (int i = 0; i < 16; ++i) {
        st0[i] = FLTMAX; st1[i] = FLTMAX; st2[i] = FLTMAX; stx[i] = 0.0f;
    }
    #pragma unroll
    for (int ni = 0; ni < 4; ++ni) {
        float sc = scn[ni];
        #pragma unroll
        for (int mi = 0; mi < 4; ++mi)
            #pragma unroll
            for (int j = 0; j < 4; ++j) {
                int idx = mi * 4 + j;
                float d2v = fmaf(-2.0f, acc[mi][ni][j], sr[idx] + sc);
                float lo0 = fminf(st0[idx], d2v), hi0 = fmaxf(st0[idx], d2v);
                st0[idx] = lo0;
                float lo1 = fminf(st1[idx], hi0), hi1 = fmaxf(st1[idx], hi0);
                st1[idx] = lo1;
                st2[idx] = fminf(st2[idx], hi1);
                stx[idx] = fmaxf(stx[idx], d2v);
            }
    }
    #pragma unroll
    for (int s = 1; s < 16; s <<= 1) {
        #pragma unroll
        for (int i = 0; i < 16; ++i) {
            float b0 = __shfl_xor(st0[i], s);
            float b1 = __shfl_xor(st1[i], s);
            float b2 = __shfl_xor(st2[i], s);
            float bm = __shfl_xor(stx[i], s);
            float n0 = fminf(st0[i], b0);
            float n1 = fminf(fmaxf(st0[i], b0), fminf(st1[i], b1));
            float n2 = fminf(fminf(st2[i], b2),
                             fminf(fmaxf(st0[i], b1), fmaxf(st1[i], b0)));
            st0[i] = n0; st1[i] = n1; st2[i] = n2; stx[i] = fmaxf(stx[i], bm);
        }
    }
    if ((l & 15) == 0) {
        const int g = l >> 4;
        const int slot = 2 * J + wn;
        #pragma unroll
        for (int mi = 0; mi < 4; ++mi)
            #pragma unroll
            for (int j = 0; j < 4; ++j) {
                int row = r0 + wm * 64 + mi * 16 + g * 4 + j;
                part4[(size_t)slot * NROWS + row] =
                    make_float4(st0[mi * 4 + j], st1[mi * 4 + j],
                                st2[mi * 4 + j], stx[mi * 4 + j]);
            }
    }

    // ---- col-side fold: rows of block J over this tile's 128 rows ----
    if (J > I) {
        float c0s[4], c1s[4], c2s[4], cxs[4];
        #pragma unroll
        for (int ni = 0; ni < 4; ++ni) {
            c0s[ni] = FLTMAX; c1s[ni] = FLTMAX; c2s[ni] = FLTMAX; cxs[ni] = 0.0f;
        }
        #pragma unroll
        for (int ni = 0; ni < 4; ++ni) {
            float sc = scn[ni];
            #pragma unroll
            for (int mi = 0; mi < 4; ++mi)
                #pragma unroll
                for (int j = 0; j < 4; ++j) {
                    float d2v = fmaf(-2.0f, acc[mi][ni][j], sr[mi * 4 + j] + sc);
                    float lo0 = fminf(c0s[ni], d2v), hi0 = fmaxf(c0s[ni], d2v);
                    c0s[ni] = lo0;
                    float lo1 = fminf(c1s[ni], hi0), hi1 = fmaxf(c1s[ni], hi0);
                    c1s[ni] = lo1;
                    c2s[ni] = fminf(c2s[ni], hi1);
                    cxs[ni] = fmaxf(cxs[ni], d2v);
                }
        }
        #pragma unroll
        for (int s = 16; s < 64; s <<= 1) {
            #pragma unroll
            for (int ni = 0; ni < 4; ++ni) {
                float b0 = __shfl_xor(c0s[ni], s);
                float b1 = __shfl_xor(c1s[ni], s);
                float b2 = __shfl_xor(c2s[ni], s);
                float bm = __shfl_xor(cxs[ni], s);
                float n0 = fminf(c0s[ni], b0);
                float n1 = fminf(fmaxf(c0s[ni], b0), fminf(c1s[ni], b1));
                float n2 = fminf(fminf(c2s[ni], b2),
                                 fminf(fmaxf(c0s[ni], b1), fmaxf(c1s[ni], b0)));
                c0s[ni] = n0; c1s[ni] = n1; c2s[ni] = n2; cxs[ni] = fmaxf(cxs[ni], bm);
            }
        }
        if (l < 16) {
            const int slot = 2 * I + wm;
            #pragma unroll
            for (int ni = 0; ni < 4; ++ni) {
                int colr = c0 + wn * 64 + ni * 16 + l;
                part4[(size_t)slot * NROWS + colr] =
                    make_float4(c0s[ni], c1s[ni], c2s[ni], cxs[ni]);
            }
        }
    }
}

// combine: fold all 64 slots per row (each written exactly once), sqrt + pred.
__global__ __launch_bounds__(256) void combine_kernel(const float4* __restrict__ part4,
                                                      float* __restrict__ out) {
    const int row = blockIdx.x * 256 + threadIdx.x;
    float m0 = FLTMAX, m1 = FLTMAX, m2 = FLTMAX, mx = 0.0f;
    for (int s = 0; s < 64; ++s) {
        float4 t = part4[(size_t)s * NROWS + row];
        float n0 = fminf(m0, t.x);
        float n1 = fminf(fmaxf(m0, t.x), fminf(m1, t.y));
        float n2 = fminf(fminf(m2, t.z), fminf(fmaxf(m0, t.y), fmaxf(m1, t.x)));
        m0 = n0; m1 = n1; m2 = n2; mx = fmaxf(mx, t.w);
    }
    float d1 = sqrtf(fmaxf(m1, 0.0f) + 1e-12f);
    float d2 = sqrtf(fmaxf(m2, 0.0f) + 1e-12f);
    float dm = sqrtf(fmaxf(mx, 0.0f) + 1e-12f);
    out[row] = (d1 / d2 < 0.6f) ? 2.0f / (1.0f + expf(d1))
                                : 2.0f / (1.0f + 2.0f * expf(dm));
}

// ============================================================================
// Path B (fallback, fp32 VALU) if ws too small
// ============================================================================

__global__ __launch_bounds__(256) void sq_kernel(const float* __restrict__ x,
                                                 float* __restrict__ sq) {
    int wid = threadIdx.x >> 6;
    int lane = threadIdx.x & 63;
    int row = blockIdx.x * 4 + wid;
    const float* f = x + (size_t)row * CDIM;
    float4 v0 = *(const float4*)(f + lane * 8);
    float4 v1 = *(const float4*)(f + lane * 8 + 4);
    float s = v0.x*v0.x + v0.y*v0.y + v0.z*v0.z + v0.w*v0.w
            + v1.x*v1.x + v1.y*v1.y + v1.z*v1.z + v1.w*v1.w;
    #pragma unroll
    for (int o = 32; o > 0; o >>= 1) s += __shfl_xor(s, o);
    if (lane == 0) sq[row] = s;
}

__global__ __launch_bounds__(256, 2) void fcm_kernel(const float* __restrict__ x,
                                                     const float* __restrict__ sq,
                                                     float* __restrict__ out) {
    __shared__ __align__(16) float a_s[32][36];
    __shared__ __align__(16) float b_s[32][260];
    const int tid = threadIdx.x;
    const int ty = tid >> 6;
    const int tx = tid & 63;
    const int brow = blockIdx.x * 32;
    const int batch = brow >> 12;
    const int irow = brow & (NPTS - 1);
    const float* f = x + (size_t)batch * NPTS * CDIM;
    const float* sqb = sq + batch * NPTS;

    float srr[8];
    #pragma unroll
    for (int r = 0; r < 8; ++r) srr[r] = sqb[irow + ty * 8 + r];
    float m0[8], m1[8], m2[8], mx[8];
    #pragma unroll
    for (int r = 0; r < 8; ++r) {
        m0[r] = FLTMAX; m1[r] = FLTMAX; m2[r] = FLTMAX; mx[r] = 0.0f;
    }
    for (int ct = 0; ct < NPTS / 256; ++ct) {
        const int cbase = ct * 256;
        float acc[8][4];
        #pragma unroll
        for (int r = 0; r < 8; ++r)
            #pragma unroll
            for (int q = 0; q < 4; ++q) acc[r][q] = 0.0f;
        for (int kc = 0; kc < CDIM; kc += 32) {
            {
                int row = tid >> 3, l8 = tid & 7;
                float4 v = *(const float4*)(f + (size_t)(irow + row) * CDIM + kc + l8 * 4);
                a_s[l8 * 4 + 0][row] = v.x; a_s[l8 * 4 + 1][row] = v.y;
                a_s[l8 * 4 + 2][row] = v.z; a_s[l8 * 4 + 3][row] = v.w;
            }
            {
                int colb = tid >> 2, l4 = tid & 3;
                #pragma unroll
                for (int it = 0; it < 4; ++it) {
                    int col = colb + 64 * it;
                    const float* p = f + (size_t)(cbase + col) * CDIM + kc + l4 * 8;
                    float4 v0 = *(const float4*)p;
                    float4 v1 = *(const float4*)(p + 4);
                    b_s[l4 * 8 + 0][col] = v0.x; b_s[l4 * 8 + 1][col] = v0.y;
                    b_s[l4 * 8 + 2][col] = v0.z; b_s[l4 * 8 + 3][col] = v0.w;
                    b_s[l4 * 8 + 4][col] = v1.x; b_s[l4 * 8 + 5][col] = v1.y;
                    b_s[l4 * 8 + 6][col] = v1.z; b_s[l4 * 8 + 7][col] = v1.w;
                }
            }
            __syncthreads();
            #pragma unroll
            for (int k = 0; k < 32; ++k) {
                float a0[8], b0[4];
                *(float4*)&a0[0] = *(const float4*)&a_s[k][ty * 8];
                *(float4*)&a0[4] = *(const float4*)&a_s[k][ty * 8 + 4];
                *(float4*)&b0[0] = *(const float4*)&b_s[k][tx * 4];
                #pragma unroll
                for (int r = 0; r < 8; ++r)
                    #pragma unroll
                    for (int q = 0; q < 4; ++q)
                        acc[r][q] = fmaf(a0[r], b0[q], acc[r][q]);
            }
            __syncthreads();
        }
        #pragma unroll
        for (int q = 0; q < 4; ++q) {
            float sc = sqb[cbase + tx * 4 + q];
            #pragma unroll
            for (int r = 0; r < 8; ++r) {
                float d2v = fmaf(-2.0f, acc[r][q], srr[r] + sc);
                d2v = fmaxf(d2v, 0.0f);
                float d = sqrtf(d2v + 1e-12f);
                float lo = fminf(m0[r], d), hi = fmaxf(m0[r], d);
                m0[r] = lo;
                float lo1 = fminf(m1[r], hi), hi1 = fmaxf(m1[r], hi);
                m1[r] = lo1;
                m2[r] = fminf(m2[r], hi1);
                mx[r] = fmaxf(mx[r], d);
            }
        }
    }
    #pragma unroll
    for (int s = 1; s < 64; s <<= 1) {
        #pragma unroll
        for (int r = 0; r < 8; ++r) {
            float b0v = __shfl_xor(m0[r], s);
            float b1v = __shfl_xor(m1[r], s);
            float b2v = __shfl_xor(m2[r], s);
            float bmv = __shfl_xor(mx[r], s);
            float n0 = fminf(m0[r], b0v);
            float n1 = fminf(fmaxf(m0[r], b0v), fminf(m1[r], b1v));
            float n2 = fminf(fminf(m2[r], b2v),
                             fminf(fmaxf(m0[r], b1v), fmaxf(m1[r], b0v)));
            m0[r] = n0; m1[r] = n1; m2[r] = n2; mx[r] = fmaxf(mx[r], bmv);
        }
    }
    if (tx == 0) {
        #pragma unroll
        for (int r = 0; r < 8; ++r) {
            int grow = brow + ty * 8 + r;
            float d1 = m1[r], d2nd = m2[r], dmaxv = mx[r];
            float pred = (d1 / d2nd < 0.6f) ? 2.0f / (1.0f + expf(d1))
                                            : 2.0f / (1.0f + 2.0f * expf(dmaxv));
            out[grow] = pred;
        }
    }
}

extern "C" void kernel_launch(void* const* d_in, const int* in_sizes, int n_in,
                              void* d_out, int out_size, void* d_ws, size_t ws_size,
                              hipStream_t stream) {
    const float* x = (const float*)d_in[0];
    float* out = (float*)d_out;

    const size_t plane = (size_t)NROWS * CDIM * sizeof(half_t);      // 16 MB
    const size_t partb = (size_t)64 * NROWS * sizeof(float4);        // 16 MB
    const size_t need = plane + NROWS * sizeof(float) + partb;

    if (ws_size >= need) {
        half_t* hi = (half_t*)d_ws;
        float* sq = (float*)((char*)d_ws + plane);
        float4* part4 = (float4*)((char*)d_ws + plane + NROWS * sizeof(float));
        prep_kernel<<<dim3(NROWS / 4), dim3(256), 0, stream>>>(x, hi, sq);
        fcm_sym<<<dim3(4 * NTILES), dim3(512), 0, stream>>>(hi, sq, part4);
        combine_kernel<<<dim3(NROWS / 256), dim3(256), 0, stream>>>(part4, out);
    } else {
        float* sqw = (float*)d_ws;
        sq_kernel<<<dim3(4096), dim3(256), 0, stream>>>(x, sqw);
        fcm_kernel<<<dim3(512), dim3(256), 0, stream>>>(x, sqw, out);
    }
}

// Round 9
// 125.502 us; speedup vs baseline: 1.5748x; 1.5748x over previous
//
#include <hip/hip_runtime.h>
#include <math.h>

#define NPTS 4096
#define CDIM 512
#define NROWS 16384
#define NTILES 528   // 32*33/2 tri-tiles of 128 per batch
#define FLTMAX 3.402823466e+38f

typedef _Float16 half_t;
typedef _Float16 half8 __attribute__((ext_vector_type(8)));
typedef float f32x4 __attribute__((ext_vector_type(4)));

__device__ inline void gl_lds16(const void* g, void* l) {
    __builtin_amdgcn_global_load_lds(
        (const __attribute__((address_space(1))) uint32_t*)g,
        (__attribute__((address_space(3))) uint32_t*)l, 16, 0, 0);
}

__device__ __forceinline__ int tri_start(int i) { return 32 * i - (i * (i - 1)) / 2; }

// ============================================================================
// Path A: prep -> fcm_sym (128x128 tri tiles, 4 chained tiles per block,
// XCD-chunked order) -> combine
// Global f16 image: row stride 1024 B; 8 Kblocks of 64 ch (128 B); 16B slot s
// of each Kblock stored at position s^(row&7) (pre-baked LDS swizzle).
// ============================================================================

__global__ __launch_bounds__(256) void prep_kernel(const float* __restrict__ x,
                                                   half_t* __restrict__ hi,
                                                   float* __restrict__ sq) {
    const int wv = threadIdx.x >> 6, l = threadIdx.x & 63;
    const int row = blockIdx.x * 4 + wv;
    const float* f = x + (size_t)row * CDIM;
    float4 v0 = *(const float4*)(f + l * 8);
    float4 v1 = *(const float4*)(f + l * 8 + 4);
    float xs[8] = {v0.x, v0.y, v0.z, v0.w, v1.x, v1.y, v1.z, v1.w};
    half8 h;
    float s = 0.0f;
    #pragma unroll
    for (int i = 0; i < 8; ++i) {
        float v = xs[i];
        s = fmaf(v, v, s);
        h[i] = (half_t)v;
    }
    #pragma unroll
    for (int o = 32; o > 0; o >>= 1) s += __shfl_xor(s, o);
    const int kb = l >> 3;
    const int pos = (l & 7) ^ (row & 7);
    *(half8*)(hi + (size_t)row * CDIM + kb * 64 + pos * 8) = h;
    if (l == 0) sq[row] = s;
}

// Each block processes 4 consecutive triangular tiles (I,J) of the XCD-chunked
// (I,J)-sorted order (528 blocks = 8 XCDs x 66, bijective; 4 tiles/chunk stay
// within one batch since 528 % 4 == 0). Per tile: 128x128, 4 waves (2x2,
// 64x64 each), BK=64, double-buffered LDS via global_load_lds; the staging
// pipeline flows continuously across tile boundaries (next tile's ks=0 staged
// during current tile's ks=7). Epilogue per tile: row-side fold -> slot 2J+wn;
// col-side fold (skip if I==J) -> slot 2I+wm.
// part layout: [slot][row] float4 (m0,m1,m2,max), d^2 domain.
__global__ __launch_bounds__(256, 2) void fcm_sym(const half_t* __restrict__ hi,
                                                  const float* __restrict__ sq,
                                                  float4* __restrict__ part4) {
    __shared__ __align__(16) char smem[2][2][16384];
    const int tid = threadIdx.x, wv = tid >> 6, l = tid & 63;
    const int wm = wv >> 1, wn = wv & 1;
    const int b = blockIdx.x;
    const int cblk = (b & 7) * 66 + (b >> 3);         // XCD-chunked, bijective
    const int gt0 = cblk * 4;
    const int batch = gt0 / NTILES;
    const int t0 = gt0 - batch * NTILES;
    int I = (int)((65.0f - sqrtf(4225.0f - 8.0f * (float)t0)) * 0.5f);
    while (tri_start(I + 1) <= t0) ++I;
    while (tri_start(I) > t0) --I;
    int J = I + (t0 - tri_start(I));
    const int bb = batch << 12;
    int r0 = bb + I * 128, c0 = bb + J * 128;
    const char* base = (const char*)hi;

    // fragment byte offsets within A/B LDS buffers (constant per thread)
    int aoff[4][2], boff[4][2];
    #pragma unroll
    for (int q = 0; q < 4; ++q)
        #pragma unroll
        for (int kc = 0; kc < 2; ++kc) {
            int rowa = wm * 64 + q * 16 + (l & 15);
            aoff[q][kc] = rowa * 128 + ((((l >> 4) + kc * 4) ^ (rowa & 7)) * 16);
            int rowb = wn * 64 + q * 16 + (l & 15);
            boff[q][kc] = rowb * 128 + ((((l >> 4) + kc * 4) ^ (rowb & 7)) * 16);
        }

    int srow[4], sin[4];
    #pragma unroll
    for (int i = 0; i < 4; ++i) {
        int dl = i * 4096 + wv * 1024 + l * 16;
        srow[i] = dl >> 7;
        sin[i] = dl & 127;
    }

#define STAGE(buf, rr, cc, ksv) do {                                           \
        _Pragma("unroll")                                                      \
        for (int i_ = 0; i_ < 4; ++i_) {                                       \
            const int db_ = i_ * 4096 + wv * 1024;                             \
            gl_lds16(base + (size_t)((rr) + srow[i_]) * 1024 + (ksv) * 128 + sin[i_], \
                     &smem[buf][0][db_]);                                      \
            gl_lds16(base + (size_t)((cc) + srow[i_]) * 1024 + (ksv) * 128 + sin[i_], \
                     &smem[buf][1][db_]);                                      \
        } } while (0)

    STAGE(0, r0, c0, 0);
    __syncthreads();

    for (int tt = 0; tt < 4; ++tt) {
        // next tile coords (for cross-tile staging; unused beyond tt==3)
        int nI = I, nJ = J + 1;
        if (nJ == 32) { nI = I + 1; nJ = nI; }
        const int nr0 = bb + nI * 128, nc0 = bb + nJ * 128;

        f32x4 acc[4][4];
        #pragma unroll
        for (int mi = 0; mi < 4; ++mi)
            #pragma unroll
            for (int ni = 0; ni < 4; ++ni)
                #pragma unroll
                for (int j = 0; j < 4; ++j) acc[mi][ni][j] = 0.0f;

        #pragma unroll
        for (int ks = 0; ks < 8; ++ks) {
            const int cur = ks & 1;
            if (ks < 7) STAGE(cur ^ 1, r0, c0, ks + 1);
            else if (tt < 3) STAGE(cur ^ 1, nr0, nc0, 0);
            #pragma unroll
            for (int kc = 0; kc < 2; ++kc) {
                half8 af[4], bf[4];
                #pragma unroll
                for (int q = 0; q < 4; ++q) {
                    af[q] = *(const half8*)&smem[cur][0][aoff[q][kc]];
                    bf[q] = *(const half8*)&smem[cur][1][boff[q][kc]];
                }
                #pragma unroll
                for (int mi = 0; mi < 4; ++mi)
                    #pragma unroll
                    for (int ni = 0; ni < 4; ++ni)
                        acc[mi][ni] = __builtin_amdgcn_mfma_f32_16x16x32_f16(
                            af[mi], bf[ni], acc[mi][ni], 0, 0, 0);
            }
            __syncthreads();
        }

        // ---- epilogue for this tile ----
        float sr[16];
        #pragma unroll
        for (int mi = 0; mi < 4; ++mi)
            #pragma unroll
            for (int j = 0; j < 4; ++j)
                sr[mi * 4 + j] = sq[r0 + wm * 64 + mi * 16 + (l >> 4) * 4 + j];
        float scn[4];
        #pragma unroll
        for (int ni = 0; ni < 4; ++ni)
            scn[ni] = sq[c0 + wn * 64 + ni * 16 + (l & 15)];

        // row-side fold: rows of block I over this tile's 128 cols
        float st0[16], st1[16], st2[16], stx[16];
        #pragma unroll
        for (int i = 0; i < 16; ++i) {
            st0[i] = FLTMAX; st1[i] = FLTMAX; st2[i] = FLTMAX; stx[i] = 0.0f;
        }
        #pragma unroll
        for (int ni = 0; ni < 4; ++ni) {
            float sc = scn[ni];
            #pragma unroll
            for (int mi = 0; mi < 4; ++mi)
                #pragma unroll
                for (int j = 0; j < 4; ++j) {
                    int idx = mi * 4 + j;
                    float d2v = fmaf(-2.0f, acc[mi][ni][j], sr[idx] + sc);
                    float lo0 = fminf(st0[idx], d2v), hi0 = fmaxf(st0[idx], d2v);
                    st0[idx] = lo0;
                    float lo1 = fminf(st1[idx], hi0), hi1 = fmaxf(st1[idx], hi0);
                    st1[idx] = lo1;
                    st2[idx] = fminf(st2[idx], hi1);
                    stx[idx] = fmaxf(stx[idx], d2v);
                }
        }
        #pragma unroll
        for (int s = 1; s < 16; s <<= 1) {
            #pragma unroll
            for (int i = 0; i < 16; ++i) {
                float b0 = __shfl_xor(st0[i], s);
                float b1 = __shfl_xor(st1[i], s);
                float b2 = __shfl_xor(st2[i], s);
                float bm = __shfl_xor(stx[i], s);
                float n0 = fminf(st0[i], b0);
                float n1 = fminf(fmaxf(st0[i], b0), fminf(st1[i], b1));
                float n2 = fminf(fminf(st2[i], b2),
                                 fminf(fmaxf(st0[i], b1), fmaxf(st1[i], b0)));
                st0[i] = n0; st1[i] = n1; st2[i] = n2; stx[i] = fmaxf(stx[i], bm);
            }
        }
        if ((l & 15) == 0) {
            const int g = l >> 4;
            const int slot = 2 * J + wn;
            #pragma unroll
            for (int mi = 0; mi < 4; ++mi)
                #pragma unroll
                for (int j = 0; j < 4; ++j) {
                    int row = r0 + wm * 64 + mi * 16 + g * 4 + j;
                    part4[(size_t)slot * NROWS + row] =
                        make_float4(st0[mi * 4 + j], st1[mi * 4 + j],
                                    st2[mi * 4 + j], stx[mi * 4 + j]);
                }
        }

        // col-side fold: rows of block J over this tile's 128 rows
        if (J > I) {
            float c0s[4], c1s[4], c2s[4], cxs[4];
            #pragma unroll
            for (int ni = 0; ni < 4; ++ni) {
                c0s[ni] = FLTMAX; c1s[ni] = FLTMAX; c2s[ni] = FLTMAX; cxs[ni] = 0.0f;
            }
            #pragma unroll
            for (int ni = 0; ni < 4; ++ni) {
                float sc = scn[ni];
                #pragma unroll
                for (int mi = 0; mi < 4; ++mi)
                    #pragma unroll
                    for (int j = 0; j < 4; ++j) {
                        float d2v = fmaf(-2.0f, acc[mi][ni][j], sr[mi * 4 + j] + sc);
                        float lo0 = fminf(c0s[ni], d2v), hi0 = fmaxf(c0s[ni], d2v);
                        c0s[ni] = lo0;
                        float lo1 = fminf(c1s[ni], hi0), hi1 = fmaxf(c1s[ni], hi0);
                        c1s[ni] = lo1;
                        c2s[ni] = fminf(c2s[ni], hi1);
                        cxs[ni] = fmaxf(cxs[ni], d2v);
                    }
            }
            #pragma unroll
            for (int s = 16; s < 64; s <<= 1) {
                #pragma unroll
                for (int ni = 0; ni < 4; ++ni) {
                    float b0 = __shfl_xor(c0s[ni], s);
                    float b1 = __shfl_xor(c1s[ni], s);
                    float b2 = __shfl_xor(c2s[ni], s);
                    float bm = __shfl_xor(cxs[ni], s);
                    float n0 = fminf(c0s[ni], b0);
                    float n1 = fminf(fmaxf(c0s[ni], b0), fminf(c1s[ni], b1));
                    float n2 = fminf(fminf(c2s[ni], b2),
                                     fminf(fmaxf(c0s[ni], b1), fmaxf(c1s[ni], b0)));
                    c0s[ni] = n0; c1s[ni] = n1; c2s[ni] = n2; cxs[ni] = fmaxf(cxs[ni], bm);
                }
            }
            if (l < 16) {
                const int slot = 2 * I + wm;
                #pragma unroll
                for (int ni = 0; ni < 4; ++ni) {
                    int colr = c0 + wn * 64 + ni * 16 + l;
                    part4[(size_t)slot * NROWS + colr] =
                        make_float4(c0s[ni], c1s[ni], c2s[ni], cxs[ni]);
                }
            }
        }

        I = nI; J = nJ; r0 = nr0; c0 = nc0;
    }
#undef STAGE
}

// combine: fold all 64 slots per row (each written exactly once), sqrt + pred.
__global__ __launch_bounds__(256) void combine_kernel(const float4* __restrict__ part4,
                                                      float* __restrict__ out) {
    const int row = blockIdx.x * 256 + threadIdx.x;
    float m0 = FLTMAX, m1 = FLTMAX, m2 = FLTMAX, mx = 0.0f;
    for (int s = 0; s < 64; ++s) {
        float4 t = part4[(size_t)s * NROWS + row];
        float n0 = fminf(m0, t.x);
        float n1 = fminf(fmaxf(m0, t.x), fminf(m1, t.y));
        float n2 = fminf(fminf(m2, t.z), fminf(fmaxf(m0, t.y), fmaxf(m1, t.x)));
        m0 = n0; m1 = n1; m2 = n2; mx = fmaxf(mx, t.w);
    }
    float d1 = sqrtf(fmaxf(m1, 0.0f) + 1e-12f);
    float d2 = sqrtf(fmaxf(m2, 0.0f) + 1e-12f);
    float dm = sqrtf(fmaxf(mx, 0.0f) + 1e-12f);
    out[row] = (d1 / d2 < 0.6f) ? 2.0f / (1.0f + expf(d1))
                                : 2.0f / (1.0f + 2.0f * expf(dm));
}

// ============================================================================
// Path B (fallback, fp32 VALU) if ws too small
// ============================================================================

__global__ __launch_bounds__(256) void sq_kernel(const float* __restrict__ x,
                                                 float* __restrict__ sq) {
    int wid = threadIdx.x >> 6;
    int lane = threadIdx.x & 63;
    int row = blockIdx.x * 4 + wid;
    const float* f = x + (size_t)row * CDIM;
    float4 v0 = *(const float4*)(f + lane * 8);
    float4 v1 = *(const float4*)(f + lane * 8 + 4);
    float s = v0.x*v0.x + v0.y*v0.y + v0.z*v0.z + v0.w*v0.w
            + v1.x*v1.x + v1.y*v1.y + v1.z*v1.z + v1.w*v1.w;
    #pragma unroll
    for (int o = 32; o > 0; o >>= 1) s += __shfl_xor(s, o);
    if (lane == 0) sq[row] = s;
}

__global__ __launch_bounds__(256, 2) void fcm_kernel(const float* __restrict__ x,
                                                     const float* __restrict__ sq,
                                                     float* __restrict__ out) {
    __shared__ __align__(16) float a_s[32][36];
    __shared__ __align__(16) float b_s[32][260];
    const int tid = threadIdx.x;
    const int ty = tid >> 6;
    const int tx = tid & 63;
    const int brow = blockIdx.x * 32;
    const int batch = brow >> 12;
    const int irow = brow & (NPTS - 1);
    const float* f = x + (size_t)batch * NPTS * CDIM;
    const float* sqb = sq + batch * NPTS;

    float srr[8];
    #pragma unroll
    for (int r = 0; r < 8; ++r) srr[r] = sqb[irow + ty * 8 + r];
    float m0[8], m1[8], m2[8], mx[8];
    #pragma unroll
    for (int r = 0; r < 8; ++r) {
        m0[r] = FLTMAX; m1[r] = FLTMAX; m2[r] = FLTMAX; mx[r] = 0.0f;
    }
    for (int ct = 0; ct < NPTS / 256; ++ct) {
        const int cbase = ct * 256;
        float acc[8][4];
        #pragma unroll
        for (int r = 0; r < 8; ++r)
            #pragma unroll
            for (int q = 0; q < 4; ++q) acc[r][q] = 0.0f;
        for (int kc = 0; kc < CDIM; kc += 32) {
            {
                int row = tid >> 3, l8 = tid & 7;
                float4 v = *(const float4*)(f + (size_t)(irow + row) * CDIM + kc + l8 * 4);
                a_s[l8 * 4 + 0][row] = v.x; a_s[l8 * 4 + 1][row] = v.y;
                a_s[l8 * 4 + 2][row] = v.z; a_s[l8 * 4 + 3][row] = v.w;
            }
            {
                int colb = tid >> 2, l4 = tid & 3;
                #pragma unroll
                for (int it = 0; it < 4; ++it) {
                    int col = colb + 64 * it;
                    const float* p = f + (size_t)(cbase + col) * CDIM + kc + l4 * 8;
                    float4 v0 = *(const float4*)p;
                    float4 v1 = *(const float4*)(p + 4);
                    b_s[l4 * 8 + 0][col] = v0.x; b_s[l4 * 8 + 1][col] = v0.y;
                    b_s[l4 * 8 + 2][col] = v0.z; b_s[l4 * 8 + 3][col] = v0.w;
                    b_s[l4 * 8 + 4][col] = v1.x; b_s[l4 * 8 + 5][col] = v1.y;
                    b_s[l4 * 8 + 6][col] = v1.z; b_s[l4 * 8 + 7][col] = v1.w;
                }
            }
            __syncthreads();
            #pragma unroll
            for (int k = 0; k < 32; ++k) {
                float a0[8], b0[4];
                *(float4*)&a0[0] = *(const float4*)&a_s[k][ty * 8];
                *(float4*)&a0[4] = *(const float4*)&a_s[k][ty * 8 + 4];
                *(float4*)&b0[0] = *(const float4*)&b_s[k][tx * 4];
                #pragma unroll
                for (int r = 0; r < 8; ++r)
                    #pragma unroll
                    for (int q = 0; q < 4; ++q)
                        acc[r][q] = fmaf(a0[r], b0[q], acc[r][q]);
            }
            __syncthreads();
        }
        #pragma unroll
        for (int q = 0; q < 4; ++q) {
            float sc = sqb[cbase + tx * 4 + q];
            #pragma unroll
            for (int r = 0; r < 8; ++r) {
                float d2v = fmaf(-2.0f, acc[r][q], srr[r] + sc);
                d2v = fmaxf(d2v, 0.0f);
                float d = sqrtf(d2v + 1e-12f);
                float lo = fminf(m0[r], d), hi = fmaxf(m0[r], d);
                m0[r] = lo;
                float lo1 = fminf(m1[r], hi), hi1 = fmaxf(m1[r], hi);
                m1[r] = lo1;
                m2[r] = fminf(m2[r], hi1);
                mx[r] = fmaxf(mx[r], d);
            }
        }
    }
    #pragma unroll
    for (int s = 1; s < 64; s <<= 1) {
        #pragma unroll
        for (int r = 0; r < 8; ++r) {
            float b0v = __shfl_xor(m0[r], s);
            float b1v = __shfl_xor(m1[r], s);
            float b2v = __shfl_xor(m2[r], s);
            float bmv = __shfl_xor(mx[r], s);
            float n0 = fminf(m0[r], b0v);
            float n1 = fminf(fmaxf(m0[r], b0v), fminf(m1[r], b1v));
            float n2 = fminf(fminf(m2[r], b2v),
                             fminf(fmaxf(m0[r], b1v), fmaxf(m1[r], b0v)));
            m0[r] = n0; m1[r] = n1; m2[r] = n2; mx[r] = fmaxf(mx[r], bmv);
        }
    }
    if (tx == 0) {
        #pragma unroll
        for (int r = 0; r < 8; ++r) {
            int grow = brow + ty * 8 + r;
            float d1 = m1[r], d2nd = m2[r], dmaxv = mx[r];
            float pred = (d1 / d2nd < 0.6f) ? 2.0f / (1.0f + expf(d1))
                                            : 2.0f / (1.0f + 2.0f * expf(dmaxv));
            out[grow] = pred;
        }
    }
}

extern "C" void kernel_launch(void* const* d_in, const int* in_sizes, int n_in,
                              void* d_out, int out_size, void* d_ws, size_t ws_size,
                              hipStream_t stream) {
    const float* x = (const float*)d_in[0];
    float* out = (float*)d_out;

    const size_t plane = (size_t)NROWS * CDIM * sizeof(half_t);      // 16 MB
    const size_t partb = (size_t)64 * NROWS * sizeof(float4);        // 16 MB
    const size_t need = plane + NROWS * sizeof(float) + partb;

    if (ws_size >= need) {
        half_t* hi = (half_t*)d_ws;
        float* sq = (float*)((char*)d_ws + plane);
        float4* part4 = (float4*)((char*)d_ws + plane + NROWS * sizeof(float));
        prep_kernel<<<dim3(NROWS / 4), dim3(256), 0, stream>>>(x, hi, sq);
        fcm_sym<<<dim3(528), dim3(256), 0, stream>>>(hi, sq, part4);
        combine_kernel<<<dim3(NROWS / 256), dim3(256), 0, stream>>>(part4, out);
    } else {
        float* sqw = (float*)d_ws;
        sq_kernel<<<dim3(4096), dim3(256), 0, stream>>>(x, sqw);
        fcm_kernel<<<dim3(512), dim3(256), 0, stream>>>(x, sqw, out);
    }
}

// Round 10
// 95.703 us; speedup vs baseline: 2.0652x; 1.3114x over previous
//
#include <hip/hip_runtime.h>
#include <math.h>

#define NPTS 4096
#define CDIM 512
#define NROWS 16384
#define NTILES 528   // 32*33/2 tri-tiles of 128 per batch
#define FLTMAX 3.402823466e+38f

typedef _Float16 half_t;
typedef _Float16 half8 __attribute__((ext_vector_type(8)));
typedef float f32x4 __attribute__((ext_vector_type(4)));

__device__ inline void gl_lds16(const void* g, void* l) {
    __builtin_amdgcn_global_load_lds(
        (const __attribute__((address_space(1))) uint32_t*)g,
        (__attribute__((address_space(3))) uint32_t*)l, 16, 0, 0);
}

// Super-tile order: per batch, 4x4 super-grid of 8x8 tiles (upper triangle,
// 10 supers: 4 diagonal of 36 tri-tiles + 6 off-diag of 64). Decode t in
// [0,528) -> (I,J), J>=I. Keeps each XCD's ~64 co-resident tiles inside one
// 2 MB working set (16 x 128 rows) so staging stays L2-resident.
__device__ __forceinline__ void super_decode(int t, int& I, int& J) {
    const int cum[10] = {0, 36, 100, 164, 228, 264, 328, 392, 428, 492};
    const int si[10]  = {0, 0, 0, 0, 1, 1, 1, 2, 2, 3};
    const int sj[10]  = {0, 1, 2, 3, 1, 2, 3, 2, 3, 3};
    int s = 0;
    #pragma unroll
    for (int k = 1; k < 10; ++k) s += (t >= cum[k]);
    const int u = t - cum[s];
    int i, j;
    if (si[s] == sj[s]) {                 // diagonal super: upper-tri 8x8
        i = 0;
        #pragma unroll
        for (int k = 1; k < 8; ++k) {
            const int c8 = k * 8 - (k * (k - 1)) / 2;
            i += (u >= c8);
        }
        const int c8i = i * 8 - (i * (i - 1)) / 2;
        j = i + (u - c8i);
    } else {                              // off-diagonal super: full 8x8
        i = u >> 3;
        j = u & 7;
    }
    I = si[s] * 8 + i;
    J = sj[s] * 8 + j;
}

// ============================================================================
// Path A: prep -> fcm_sym (128x128 tri tiles, super-tile XCD-chunked order)
// -> combine
// Global f16 image: row stride 1024 B; 8 Kblocks of 64 ch (128 B); 16B slot s
// of each Kblock stored at position s^(row&7) (pre-baked LDS swizzle).
// ============================================================================

__global__ __launch_bounds__(256) void prep_kernel(const float* __restrict__ x,
                                                   half_t* __restrict__ hi,
                                                   float* __restrict__ sq) {
    const int wv = threadIdx.x >> 6, l = threadIdx.x & 63;
    const int row = blockIdx.x * 4 + wv;
    const float* f = x + (size_t)row * CDIM;
    float4 v0 = *(const float4*)(f + l * 8);
    float4 v1 = *(const float4*)(f + l * 8 + 4);
    float xs[8] = {v0.x, v0.y, v0.z, v0.w, v1.x, v1.y, v1.z, v1.w};
    half8 h;
    float s = 0.0f;
    #pragma unroll
    for (int i = 0; i < 8; ++i) {
        float v = xs[i];
        s = fmaf(v, v, s);
        h[i] = (half_t)v;
    }
    #pragma unroll
    for (int o = 32; o > 0; o >>= 1) s += __shfl_xor(s, o);
    const int kb = l >> 3;
    const int pos = (l & 7) ^ (row & 7);
    *(half8*)(hi + (size_t)row * CDIM + kb * 64 + pos * 8) = h;
    if (l == 0) sq[row] = s;
}

// One block per triangular tile (I,J), J>=I, per batch. 128x128 tile, 4 waves
// (2x2, 64x64 each), BK=64, double-buffered LDS via global_load_lds.
// Tile order: super-tile (8x8-tile) blocks, XCD-chunked (2112 = 8 x 264;
// 264 is an exact super boundary) so each XCD's resident staging working set
// is ~2 MB and stays in its private L2.
// Epilogue: row-side fold -> slot 2J+wn; col-side fold (skip if I==J)
//   -> slot 2I+wm. part layout: [slot][row] float4 (m0,m1,m2,max), d^2 domain.
__global__ __launch_bounds__(256, 2) void fcm_sym(const half_t* __restrict__ hi,
                                                  const float* __restrict__ sq,
                                                  float4* __restrict__ part4) {
    __shared__ __align__(16) char smem[2][2][16384];
    const int tid = threadIdx.x, wv = tid >> 6, l = tid & 63;
    const int wm = wv >> 1, wn = wv & 1;
    const int wg = blockIdx.x;
    const int tl = (wg & 7) * 264 + (wg >> 3);        // XCD-chunked, bijective
    const int batch = tl / NTILES;
    const int t = tl - batch * NTILES;
    int I, J;
    super_decode(t, I, J);
    const int r0 = (batch << 12) + I * 128;
    const int c0 = (batch << 12) + J * 128;
    const char* base = (const char*)hi;

    float sr[16];
    #pragma unroll
    for (int mi = 0; mi < 4; ++mi)
        #pragma unroll
        for (int j = 0; j < 4; ++j)
            sr[mi * 4 + j] = sq[r0 + wm * 64 + mi * 16 + (l >> 4) * 4 + j];
    float scn[4];
    #pragma unroll
    for (int ni = 0; ni < 4; ++ni)
        scn[ni] = sq[c0 + wn * 64 + ni * 16 + (l & 15)];

    // fragment byte offsets within A/B LDS buffers (constant per thread)
    int aoff[4][2], boff[4][2];
    #pragma unroll
    for (int q = 0; q < 4; ++q)
        #pragma unroll
        for (int kc = 0; kc < 2; ++kc) {
            int rowa = wm * 64 + q * 16 + (l & 15);
            aoff[q][kc] = rowa * 128 + ((((l >> 4) + kc * 4) ^ (rowa & 7)) * 16);
            int rowb = wn * 64 + q * 16 + (l & 15);
            boff[q][kc] = rowb * 128 + ((((l >> 4) + kc * 4) ^ (rowb & 7)) * 16);
        }

    int srow[4], sin[4];
    #pragma unroll
    for (int i = 0; i < 4; ++i) {
        int dl = i * 4096 + wv * 1024 + l * 16;
        srow[i] = dl >> 7;
        sin[i] = dl & 127;
    }

#define STAGE(buf, ksv) do {                                                   \
        _Pragma("unroll")                                                      \
        for (int i_ = 0; i_ < 4; ++i_) {                                       \
            const int db_ = i_ * 4096 + wv * 1024;                             \
            gl_lds16(base + (size_t)(r0 + srow[i_]) * 1024 + (ksv) * 128 + sin[i_], \
                     &smem[buf][0][db_]);                                      \
            gl_lds16(base + (size_t)(c0 + srow[i_]) * 1024 + (ksv) * 128 + sin[i_], \
                     &smem[buf][1][db_]);                                      \
        } } while (0)

    f32x4 acc[4][4];
    #pragma unroll
    for (int mi = 0; mi < 4; ++mi)
        #pragma unroll
        for (int ni = 0; ni < 4; ++ni)
            #pragma unroll
            for (int j = 0; j < 4; ++j) acc[mi][ni][j] = 0.0f;

    STAGE(0, 0);
    __syncthreads();
    #pragma unroll
    for (int ks = 0; ks < 8; ++ks) {
        const int cur = ks & 1;
        if (ks < 7) STAGE(cur ^ 1, ks + 1);
        #pragma unroll
        for (int kc = 0; kc < 2; ++kc) {
            half8 af[4], bf[4];
            #pragma unroll
            for (int q = 0; q < 4; ++q) {
                af[q] = *(const half8*)&smem[cur][0][aoff[q][kc]];
                bf[q] = *(const half8*)&smem[cur][1][boff[q][kc]];
            }
            #pragma unroll
            for (int mi = 0; mi < 4; ++mi)
                #pragma unroll
                for (int ni = 0; ni < 4; ++ni)
                    acc[mi][ni] = __builtin_amdgcn_mfma_f32_16x16x32_f16(
                        af[mi], bf[ni], acc[mi][ni], 0, 0, 0);
        }
        __syncthreads();
    }
#undef STAGE

    // ---- row-side fold: rows of block I over this tile's 128 cols ----
    float st0[16], st1[16], st2[16], stx[16];
    #pragma unroll
    for (int i = 0; i < 16; ++i) {
        st0[i] = FLTMAX; st1[i] = FLTMAX; st2[i] = FLTMAX; stx[i] = 0.0f;
    }
    #pragma unroll
    for (int ni = 0; ni < 4; ++ni) {
        float sc = scn[ni];
        #pragma unroll
        for (int mi = 0; mi < 4; ++mi)
            #pragma unroll
            for (int j = 0; j < 4; ++j) {
                int idx = mi * 4 + j;
                float d2v = fmaf(-2.0f, acc[mi][ni][j], sr[idx] + sc);
                float lo0 = fminf(st0[idx], d2v), hi0 = fmaxf(st0[idx], d2v);
                st0[idx] = lo0;
                float lo1 = fminf(st1[idx], hi0), hi1 = fmaxf(st1[idx], hi0);
                st1[idx] = lo1;
                st2[idx] = fminf(st2[idx], hi1);
                stx[idx] = fmaxf(stx[idx], d2v);
            }
    }
    #pragma unroll
    for (int s = 1; s < 16; s <<= 1) {
        #pragma unroll
        for (int i = 0; i < 16; ++i) {
            float b0 = __shfl_xor(st0[i], s);
            float b1 = __shfl_xor(st1[i], s);
            float b2 = __shfl_xor(st2[i], s);
            float bm = __shfl_xor(stx[i], s);
            float n0 = fminf(st0[i], b0);
            float n1 = fminf(fmaxf(st0[i], b0), fminf(st1[i], b1));
            float n2 = fminf(fminf(st2[i], b2),
                             fminf(fmaxf(st0[i], b1), fmaxf(st1[i], b0)));
            st0[i] = n0; st1[i] = n1; st2[i] = n2; stx[i] = fmaxf(stx[i], bm);
        }
    }
    if ((l & 15) == 0) {
        const int g = l >> 4;
        const int slot = 2 * J + wn;
        #pragma unroll
        for (int mi = 0; mi < 4; ++mi)
            #pragma unroll
            for (int j = 0; j < 4; ++j) {
                int row = r0 + wm * 64 + mi * 16 + g * 4 + j;
                part4[(size_t)slot * NROWS + row] =
                    make_float4(st0[mi * 4 + j], st1[mi * 4 + j],
                                st2[mi * 4 + j], stx[mi * 4 + j]);
            }
    }

    // ---- col-side fold: rows of block J over this tile's 128 rows ----
    if (J > I) {
        float c0s[4], c1s[4], c2s[4], cxs[4];
        #pragma unroll
        for (int ni = 0; ni < 4; ++ni) {
            c0s[ni] = FLTMAX; c1s[ni] = FLTMAX; c2s[ni] = FLTMAX; cxs[ni] = 0.0f;
        }
        #pragma unroll
        for (int ni = 0; ni < 4; ++ni) {
            float sc = scn[ni];
            #pragma unroll
            for (int mi = 0; mi < 4; ++mi)
                #pragma unroll
                for (int j = 0; j < 4; ++j) {
                    float d2v = fmaf(-2.0f, acc[mi][ni][j], sr[mi * 4 + j] + sc);
                    float lo0 = fminf(c0s[ni], d2v), hi0 = fmaxf(c0s[ni], d2v);
                    c0s[ni] = lo0;
                    float lo1 = fminf(c1s[ni], hi0), hi1 = fmaxf(c1s[ni], hi0);
                    c1s[ni] = lo1;
                    c2s[ni] = fminf(c2s[ni], hi1);
                    cxs[ni] = fmaxf(cxs[ni], d2v);
                }
        }
        #pragma unroll
        for (int s = 16; s < 64; s <<= 1) {
            #pragma unroll
            for (int ni = 0; ni < 4; ++ni) {
                float b0 = __shfl_xor(c0s[ni], s);
                float b1 = __shfl_xor(c1s[ni], s);
                float b2 = __shfl_xor(c2s[ni], s);
                float bm = __shfl_xor(cxs[ni], s);
                float n0 = fminf(c0s[ni], b0);
                float n1 = fminf(fmaxf(c0s[ni], b0), fminf(c1s[ni], b1));
                float n2 = fminf(fminf(c2s[ni], b2),
                                 fminf(fmaxf(c0s[ni], b1), fmaxf(c1s[ni], b0)));
                c0s[ni] = n0; c1s[ni] = n1; c2s[ni] = n2; cxs[ni] = fmaxf(cxs[ni], bm);
            }
        }
        if (l < 16) {
            const int slot = 2 * I + wm;
            #pragma unroll
            for (int ni = 0; ni < 4; ++ni) {
                int colr = c0 + wn * 64 + ni * 16 + l;
                part4[(size_t)slot * NROWS + colr] =
                    make_float4(c0s[ni], c1s[ni], c2s[ni], cxs[ni]);
            }
        }
    }
}

// combine: fold all 64 slots per row (each written exactly once), sqrt + pred.
__global__ __launch_bounds__(256) void combine_kernel(const float4* __restrict__ part4,
                                                      float* __restrict__ out) {
    const int row = blockIdx.x * 256 + threadIdx.x;
    float m0 = FLTMAX, m1 = FLTMAX, m2 = FLTMAX, mx = 0.0f;
    for (int s = 0; s < 64; ++s) {
        float4 t = part4[(size_t)s * NROWS + row];
        float n0 = fminf(m0, t.x);
        float n1 = fminf(fmaxf(m0, t.x), fminf(m1, t.y));
        float n2 = fminf(fminf(m2, t.z), fminf(fmaxf(m0, t.y), fmaxf(m1, t.x)));
        m0 = n0; m1 = n1; m2 = n2; mx = fmaxf(mx, t.w);
    }
    float d1 = sqrtf(fmaxf(m1, 0.0f) + 1e-12f);
    float d2 = sqrtf(fmaxf(m2, 0.0f) + 1e-12f);
    float dm = sqrtf(fmaxf(mx, 0.0f) + 1e-12f);
    out[row] = (d1 / d2 < 0.6f) ? 2.0f / (1.0f + expf(d1))
                                : 2.0f / (1.0f + 2.0f * expf(dm));
}

// ============================================================================
// Path B (fallback, fp32 VALU) if ws too small
// ============================================================================

__global__ __launch_bounds__(256) void sq_kernel(const float* __restrict__ x,
                                                 float* __restrict__ sq) {
    int wid = threadIdx.x >> 6;
    int lane = threadIdx.x & 63;
    int row = blockIdx.x * 4 + wid;
    const float* f = x + (size_t)row * CDIM;
    float4 v0 = *(const float4*)(f + lane * 8);
    float4 v1 = *(const float4*)(f + lane * 8 + 4);
    float s = v0.x*v0.x + v0.y*v0.y + v0.z*v0.z + v0.w*v0.w
            + v1.x*v1.x + v1.y*v1.y + v1.z*v1.z + v1.w*v1.w;
    #pragma unroll
    for (int o = 32; o > 0; o >>= 1) s += __shfl_xor(s, o);
    if (lane == 0) sq[row] = s;
}

__global__ __launch_bounds__(256, 2) void fcm_kernel(const float* __restrict__ x,
                                                     const float* __restrict__ sq,
                                                     float* __restrict__ out) {
    __shared__ __align__(16) float a_s[32][36];
    __shared__ __align__(16) float b_s[32][260];
    const int tid = threadIdx.x;
    const int ty = tid >> 6;
    const int tx = tid & 63;
    const int brow = blockIdx.x * 32;
    const int batch = brow >> 12;
    const int irow = brow & (NPTS - 1);
    const float* f = x + (size_t)batch * NPTS * CDIM;
    const float* sqb = sq + batch * NPTS;

    float srr[8];
    #pragma unroll
    for (int r = 0; r < 8; ++r) srr[r] = sqb[irow + ty * 8 + r];
    float m0[8], m1[8], m2[8], mx[8];
    #pragma unroll
    for (int r = 0; r < 8; ++r) {
        m0[r] = FLTMAX; m1[r] = FLTMAX; m2[r] = FLTMAX; mx[r] = 0.0f;
    }
    for (int ct = 0; ct < NPTS / 256; ++ct) {
        const int cbase = ct * 256;
        float acc[8][4];
        #pragma unroll
        for (int r = 0; r < 8; ++r)
            #pragma unroll
            for (int q = 0; q < 4; ++q) acc[r][q] = 0.0f;
        for (int kc = 0; kc < CDIM; kc += 32) {
            {
                int row = tid >> 3, l8 = tid & 7;
                float4 v = *(const float4*)(f + (size_t)(irow + row) * CDIM + kc + l8 * 4);
                a_s[l8 * 4 + 0][row] = v.x; a_s[l8 * 4 + 1][row] = v.y;
                a_s[l8 * 4 + 2][row] = v.z; a_s[l8 * 4 + 3][row] = v.w;
            }
            {
                int colb = tid >> 2, l4 = tid & 3;
                #pragma unroll
                for (int it = 0; it < 4; ++it) {
                    int col = colb + 64 * it;
                    const float* p = f + (size_t)(cbase + col) * CDIM + kc + l4 * 8;
                    float4 v0 = *(const float4*)p;
                    float4 v1 = *(const float4*)(p + 4);
                    b_s[l4 * 8 + 0][col] = v0.x; b_s[l4 * 8 + 1][col] = v0.y;
                    b_s[l4 * 8 + 2][col] = v0.z; b_s[l4 * 8 + 3][col] = v0.w;
                    b_s[l4 * 8 + 4][col] = v1.x; b_s[l4 * 8 + 5][col] = v1.y;
                    b_s[l4 * 8 + 6][col] = v1.z; b_s[l4 * 8 + 7][col] = v1.w;
                }
            }
            __syncthreads();
            #pragma unroll
            for (int k = 0; k < 32; ++k) {
                float a0[8], b0[4];
                *(float4*)&a0[0] = *(const float4*)&a_s[k][ty * 8];
                *(float4*)&a0[4] = *(const float4*)&a_s[k][ty * 8 + 4];
                *(float4*)&b0[0] = *(const float4*)&b_s[k][tx * 4];
                #pragma unroll
                for (int r = 0; r < 8; ++r)
                    #pragma unroll
                    for (int q = 0; q < 4; ++q)
                        acc[r][q] = fmaf(a0[r], b0[q], acc[r][q]);
            }
            __syncthreads();
        }
        #pragma unroll
        for (int q = 0; q < 4; ++q) {
            float sc = sqb[cbase + tx * 4 + q];
            #pragma unroll
            for (int r = 0; r < 8; ++r) {
                float d2v = fmaf(-2.0f, acc[r][q], srr[r] + sc);
                d2v = fmaxf(d2v, 0.0f);
                float d = sqrtf(d2v + 1e-12f);
                float lo = fminf(m0[r], d), hi = fmaxf(m0[r], d);
                m0[r] = lo;
                float lo1 = fminf(m1[r], hi), hi1 = fmaxf(m1[r], hi);
                m1[r] = lo1;
                m2[r] = fminf(m2[r], hi1);
                mx[r] = fmaxf(mx[r], d);
            }
        }
    }
    #pragma unroll
    for (int s = 1; s < 64; s <<= 1) {
        #pragma unroll
        for (int r = 0; r < 8; ++r) {
            float b0v = __shfl_xor(m0[r], s);
            float b1v = __shfl_xor(m1[r], s);
            float b2v = __shfl_xor(m2[r], s);
            float bmv = __shfl_xor(mx[r], s);
            float n0 = fminf(m0[r], b0v);
            float n1 = fminf(fmaxf(m0[r], b0v), fminf(m1[r], b1v));
            float n2 = fminf(fminf(m2[r], b2v),
                             fminf(fmaxf(m0[r], b1v), fmaxf(m1[r], b0v)));
            m0[r] = n0; m1[r] = n1; m2[r] = n2; mx[r] = fmaxf(mx[r], bmv);
        }
    }
    if (tx == 0) {
        #pragma unroll
        for (int r = 0; r < 8; ++r) {
            int grow = brow + ty * 8 + r;
            float d1 = m1[r], d2nd = m2[r], dmaxv = mx[r];
            float pred = (d1 / d2nd < 0.6f) ? 2.0f / (1.0f + expf(d1))
                                            : 2.0f / (1.0f + 2.0f * expf(dmaxv));
            out[grow] = pred;
        }
    }
}

extern "C" void kernel_launch(void* const* d_in, const int* in_sizes, int n_in,
                              void* d_out, int out_size, void* d_ws, size_t ws_size,
                              hipStream_t stream) {
    const float* x = (const float*)d_in[0];
    float* out = (float*)d_out;

    const size_t plane = (size_t)NROWS * CDIM * sizeof(half_t);      // 16 MB
    const size_t partb = (size_t)64 * NROWS * sizeof(float4);        // 16 MB
    const size_t need = plane + NROWS * sizeof(float) + partb;

    if (ws_size >= need) {
        half_t* hi = (half_t*)d_ws;
        float* sq = (float*)((char*)d_ws + plane);
        float4* part4 = (float4*)((char*)d_ws + plane + NROWS * sizeof(float));
        prep_kernel<<<dim3(NROWS / 4), dim3(256), 0, stream>>>(x, hi, sq);
        fcm_sym<<<dim3(4 * NTILES), dim3(256), 0, stream>>>(hi, sq, part4);
        combine_kernel<<<dim3(NROWS / 256), dim3(256), 0, stream>>>(part4, out);
    } else {
        float* sqw = (float*)d_ws;
        sq_kernel<<<dim3(4096), dim3(256), 0, stream>>>(x, sqw);
        fcm_kernel<<<dim3(512), dim3(256), 0, stream>>>(x, sqw, out);
    }
}